// Round 11
// baseline (19320.630 us; speedup 1.0000x reference)
//
#include <hip/hip_runtime.h>

// PositionCloser round 11: 2 sequences per wave, 512 blocks x 64 threads.
// R1-R10 evidence: the 128-word W_hh array is ALWAYS AGPR-parked, costing one
// v_accvgpr_read per use (~256 extra instr/step in R9 = the dominant cost);
// per-step cross-wave sync costs >=500cy (R10). Fix: interleave TWO sequences
// in one wave -- weights are shared, so each weight word is read from AGPR
// once per step-PAIR and feeds both seqs' fdot2 (tax halves per seq), and
// every latency chain gets 2-way ILP. Loss inline lag-1 (R7 bookkeeping).
// Half the SIMDs are idle (512 waves) by design; per-seq issue is the metric.

#define CH  128
#define HID 64

typedef __fp16 f16x2 __attribute__((ext_vector_type(2)));

__device__ __forceinline__ float rlf(float v, int l) {
  return __builtin_bit_cast(float, __builtin_amdgcn_readlane(__builtin_bit_cast(int, v), l));
}
__device__ __forceinline__ int rli(int v, int l) { return __builtin_amdgcn_readlane(v, l); }
__device__ __forceinline__ int packh(float a, float b) {
  return __builtin_bit_cast(int, __builtin_amdgcn_cvt_pkrtz(a, b));
}
__device__ __forceinline__ f16x2 h2(int v) { return __builtin_bit_cast(f16x2, v); }
__device__ __forceinline__ float frcp(float x) { return __builtin_amdgcn_rcpf(x); }
__device__ __forceinline__ float sigm(float x) { return frcp(1.0f + __expf(-x)); }
__device__ __forceinline__ float tanh_(float x) {
  float e = __expf(2.0f * x);
  return 1.0f - 2.0f * frcp(e + 1.0f);
}
template <int CTRL, int RMASK>
__device__ __forceinline__ float dpp_add(float v) {
  int x = __builtin_amdgcn_update_dpp(0, __builtin_bit_cast(int, v), CTRL, RMASK, 0xF, true);
  return v + __builtin_bit_cast(float, x);
}
__device__ __forceinline__ float dpp_xor1(float v) {  // quad_perm [1,0,3,2]
  int x = __builtin_amdgcn_update_dpp(0, __builtin_bit_cast(int, v), 0xB1, 0xF, 0xF, true);
  return __builtin_bit_cast(float, x);
}
__device__ __forceinline__ float dpp_wave_sum(float v) {  // total lands in lane 63
  v = dpp_add<0x111, 0xF>(v);
  v = dpp_add<0x112, 0xF>(v);
  v = dpp_add<0x114, 0xF>(v);
  v = dpp_add<0x118, 0xF>(v);
  v = dpp_add<0x142, 0xA>(v);   // row_bcast:15
  v = dpp_add<0x143, 0xC>(v);   // row_bcast:31
  return v;
}

__global__ __launch_bounds__(64, 1)
void pc_lstm_kernel(const int* __restrict__ inds,
                    const float* __restrict__ p,
                    const float* __restrict__ ls_probs,
                    const float* __restrict__ open_probs,
                    const int* __restrict__ open_slices,
                    const float* __restrict__ open_hx,
                    const float* __restrict__ W_ih,
                    const float* __restrict__ W_hh,
                    const float* __restrict__ b_ih,
                    const float* __restrict__ b_hh,
                    const float* __restrict__ W_out,
                    const float* __restrict__ b_out,
                    const int* __restrict__ n_chunks_p,
                    float* __restrict__ out)
{
  const int lane = threadIdx.x;          // 0..63 (= hid index)
  const int sa   = blockIdx.x * 2;       // sequence A
  const int sb   = sa + 1;               // sequence B
  const int n_chunks = n_chunks_p[0];

  // ---- shared recurrent weights: lane owns gate rows g*64+lane, 128 words
  int W0[32], W1[32], W2[32], W3[32];
  {
    const float2* r0 = (const float2*)(W_hh + (0 * HID + lane) * HID);
    const float2* r1 = (const float2*)(W_hh + (1 * HID + lane) * HID);
    const float2* r2 = (const float2*)(W_hh + (2 * HID + lane) * HID);
    const float2* r3 = (const float2*)(W_hh + (3 * HID + lane) * HID);
#pragma unroll
    for (int j = 0; j < 32; ++j) {
      float2 v0 = r0[j], v1 = r1[j], v2 = r2[j], v3 = r3[j];
      W0[j] = packh(v0.x, v0.y);
      W1[j] = packh(v1.x, v1.y);
      W2[j] = packh(v2.x, v2.y);
      W3[j] = packh(v3.x, v3.y);
    }
  }

  // shared per-lane input weights + fused bias + wout
  float wxa[4], wxb[4], bb[4];
#pragma unroll
  for (int g = 0; g < 4; ++g) {
    const int r = g * HID + lane;
    wxa[g] = W_ih[2 * r];
    wxb[g] = W_ih[2 * r + 1];
    bb[g]  = b_ih[r] + b_hh[r];
  }
  const float wo   = W_out[lane];
  const float bout = b_out[0];

  // ---- per-sequence state (suffix a/b)
  float ha = open_hx[(sa * 2 + 0) * HID + lane];
  float ca = open_hx[(sa * 2 + 1) * HID + lane];
  float hb = open_hx[(sb * 2 + 0) * HID + lane];
  float cb = open_hx[(sb * 2 + 1) * HID + lane];
  const int   osa = open_slices[sa], osb = open_slices[sb];
  const float OLa = __logf(p[2 * osa]) + __logf(p[2 * osa + 1]);
  const float OLb = __logf(p[2 * osb]) + __logf(p[2 * osb + 1]);
  const float coefa = open_probs[sa] * (2.0f * ls_probs[sa] - 1.0f);
  const float coefb = open_probs[sb] * (2.0f * ls_probs[sb] - 1.0f);
  const int tba = inds[sa >> 4] + (sa & 15);
  const int tbb = inds[sb >> 4] + (sb & 15);

  float Sda = 1.0f, Qda = 1.0f, lsuma = 0.0f, psuma = 0.0f;
  float Sdb = 1.0f, Qdb = 1.0f, lsumb = 0.0f, psumb = 0.0f;
  float Lcarrya = 0.0f, LAprevA = 0.0f;   // LBprev for seq a
  float Lcarryb = 0.0f, LAprevB = 0.0f;   // LBprev for seq b

  const float2* p2 = (const float2*)p;
  float2 curAa = p2[tba + lane],       curBa = p2[tba + HID + lane];
  float2 curAb = p2[tbb + lane],       curBb = p2[tbb + HID + lane];
  float2 nxtAa = curAa, nxtBa = curBa, nxtAb = curAb, nxtBb = curBb;

  for (int off = 0; off < n_chunks; ++off) {
    if (off) {
      Lcarrya = rlf(LAprevA, 63); curAa = nxtAa; curBa = nxtBa;
      Lcarryb = rlf(LAprevB, 63); curAb = nxtAb; curBb = nxtBb;
    }
    const float LAa = __logf(curAa.x) + __logf(curAa.y);
    const float LBa = __logf(curBa.x) + __logf(curBa.y);
    const float LAb = __logf(curAb.x) + __logf(curAb.y);
    const float LBb = __logf(curBb.x) + __logf(curBb.y);
    const float pxa0 = rlf(curAa.x, 0), pxa1 = rlf(curAa.y, 0);
    const float pxb0 = rlf(curAb.x, 0), pxb1 = rlf(curAb.y, 0);
    if (off + 1 < n_chunks) {
      const int na = tba + (off + 1) * CH;
      const int nb = tbb + (off + 1) * CH;
      nxtAa = p2[na + lane]; nxtBa = p2[na + HID + lane];
      nxtAb = p2[nb + lane]; nxtBb = p2[nb + HID + lane];
    }

#pragma unroll 1
    for (int tt = 0; tt < CH; ++tt) {
      // z of entering h (h_{t-1}) for both seqs -> lag-1 loss; off h-path
      const float zpa = rlf(dpp_wave_sum(ha * wo), 63);
      const float zpb = rlf(dpp_wave_sum(hb * wo), 63);

      // pack h pairs (even lane 2j holds (h_2j, h_2j+1))
      const int hpa = packh(ha, dpp_xor1(ha));
      const int hpb = packh(hb, dpp_xor1(hb));

      // fused matvec: each weight word read ONCE, used by both seqs
      float A0a = bb[0], A1a = bb[1], A2a = bb[2], A3a = bb[3];
      float A0b = bb[0], A1b = bb[1], A2b = bb[2], A3b = bb[3];
      float B0a = 0.f, B1a = 0.f, B2a = 0.f, B3a = 0.f;
      float B0b = 0.f, B1b = 0.f, B2b = 0.f, B3b = 0.f;
#pragma unroll
      for (int j = 0; j < 16; ++j) {
        const f16x2 haa = h2(rli(hpa, 2 * j));
        const f16x2 hab = h2(rli(hpa, 2 * j + 32));
        const f16x2 hba = h2(rli(hpb, 2 * j));
        const f16x2 hbb = h2(rli(hpb, 2 * j + 32));
        A0a = __builtin_amdgcn_fdot2(haa, h2(W0[j]),      A0a, false);
        A0b = __builtin_amdgcn_fdot2(hba, h2(W0[j]),      A0b, false);
        B0a = __builtin_amdgcn_fdot2(hab, h2(W0[j + 16]), B0a, false);
        B0b = __builtin_amdgcn_fdot2(hbb, h2(W0[j + 16]), B0b, false);
        A1a = __builtin_amdgcn_fdot2(haa, h2(W1[j]),      A1a, false);
        A1b = __builtin_amdgcn_fdot2(hba, h2(W1[j]),      A1b, false);
        B1a = __builtin_amdgcn_fdot2(hab, h2(W1[j + 16]), B1a, false);
        B1b = __builtin_amdgcn_fdot2(hbb, h2(W1[j + 16]), B1b, false);
        A2a = __builtin_amdgcn_fdot2(haa, h2(W2[j]),      A2a, false);
        A2b = __builtin_amdgcn_fdot2(hba, h2(W2[j]),      A2b, false);
        B2a = __builtin_amdgcn_fdot2(hab, h2(W2[j + 16]), B2a, false);
        B2b = __builtin_amdgcn_fdot2(hbb, h2(W2[j + 16]), B2b, false);
        A3a = __builtin_amdgcn_fdot2(haa, h2(W3[j]),      A3a, false);
        A3b = __builtin_amdgcn_fdot2(hba, h2(W3[j]),      A3b, false);
        B3a = __builtin_amdgcn_fdot2(hab, h2(W3[j + 16]), B3a, false);
        B3b = __builtin_amdgcn_fdot2(hbb, h2(W3[j + 16]), B3b, false);
      }

      // lag-1 loss, both seqs (wave-uniform; overlaps the dot chains)
      if (off | tt) {
        const int ltt = (tt == 0) ? (CH - 1) : (tt - 1);
        {
          const float Lt = (tt == 0) ? Lcarrya
                         : (ltt < 64) ? rlf(LAa, ltt) : rlf(LBa, ltt - 64);
          const float pr = sigm(zpa + bout);
          if (ltt == 0) Qda = 1.0f;
          const float T  = (ltt == 0) ? 1.0f : Sda * Qda;  // chunk t=0 undiscounted
          const float pn = pr * T;
          lsuma = fmaf(pn, Lt, lsuma);
          psuma += pn;
          if (ltt == CH - 1) Sda *= Qda;                   // carry excludes (1-p_last)
          Qda *= (1.0f - pr);
        }
        {
          const float Lt = (tt == 0) ? Lcarryb
                         : (ltt < 64) ? rlf(LAb, ltt) : rlf(LBb, ltt - 64);
          const float pr = sigm(zpb + bout);
          if (ltt == 0) Qdb = 1.0f;
          const float T  = (ltt == 0) ? 1.0f : Sdb * Qdb;
          const float pn = pr * T;
          lsumb = fmaf(pn, Lt, lsumb);
          psumb += pn;
          if (ltt == CH - 1) Sdb *= Qdb;
          Qdb *= (1.0f - pr);
        }
      }

      // input contribution + gates, both seqs
      {
        const float sp0 = (tt < 64) ? rlf(curAa.x, tt) : rlf(curBa.x, tt - 64);
        const float sp1 = (tt < 64) ? rlf(curAa.y, tt) : rlf(curBa.y, tt - 64);
        const float x0 = sp0 - pxa0, x1 = sp1 - pxa1;
        const float g0 = A0a + B0a + fmaf(x1, wxb[0], x0 * wxa[0]);
        const float g1 = A1a + B1a + fmaf(x1, wxb[1], x0 * wxa[1]);
        const float g2 = A2a + B2a + fmaf(x1, wxb[2], x0 * wxa[2]);
        const float g3 = A3a + B3a + fmaf(x1, wxb[3], x0 * wxa[3]);
        const float ig = sigm(g0), fg = sigm(g1), gg = tanh_(g2), og = sigm(g3);
        ca = fmaf(fg, ca, ig * gg);
        ha = og * tanh_(ca);
      }
      {
        const float sp0 = (tt < 64) ? rlf(curAb.x, tt) : rlf(curBb.x, tt - 64);
        const float sp1 = (tt < 64) ? rlf(curAb.y, tt) : rlf(curBb.y, tt - 64);
        const float x0 = sp0 - pxb0, x1 = sp1 - pxb1;
        const float g0 = A0b + B0b + fmaf(x1, wxb[0], x0 * wxa[0]);
        const float g1 = A1b + B1b + fmaf(x1, wxb[1], x0 * wxa[1]);
        const float g2 = A2b + B2b + fmaf(x1, wxb[2], x0 * wxa[2]);
        const float g3 = A3b + B3b + fmaf(x1, wxb[3], x0 * wxa[3]);
        const float ig = sigm(g0), fg = sigm(g1), gg = tanh_(g2), og = sigm(g3);
        cb = fmaf(fg, cb, ig * gg);
        hb = og * tanh_(cb);
      }
    }
    LAprevA = LBa;
    LAprevB = LBb;
  }

  // drain final step's prob (ltt = 127) for both seqs
  {
    const float z  = rlf(dpp_wave_sum(ha * wo), 63);
    const float pr = sigm(z + bout);
    const float pn = pr * Sda * Qda;
    lsuma = fmaf(pn, rlf(LAprevA, 63), lsuma);
    psuma += pn;
  }
  {
    const float z  = rlf(dpp_wave_sum(hb * wo), 63);
    const float pr = sigm(z + bout);
    const float pn = pr * Sdb * Qdb;
    lsumb = fmaf(pn, rlf(LAprevB, 63), lsumb);
    psumb += pn;
  }

  if (lane == 0)
    atomicAdd(out, coefa * (lsuma - OLa * psuma) + coefb * (lsumb - OLb * psumb));
}

extern "C" void kernel_launch(void* const* d_in, const int* in_sizes, int n_in,
                              void* d_out, int out_size, void* d_ws, size_t ws_size,
                              hipStream_t stream) {
  (void)hipMemsetAsync(d_out, 0, sizeof(float), stream);

  pc_lstm_kernel<<<dim3(512), dim3(64), 0, stream>>>(
      (const int*)d_in[0],    // inds
      (const float*)d_in[1],  // p
      (const float*)d_in[2],  // ls_probs
      (const float*)d_in[3],  // open_probs
      (const int*)d_in[4],    // open_slices
      (const float*)d_in[5],  // open_hx
      (const float*)d_in[6],  // W_ih
      (const float*)d_in[7],  // W_hh
      (const float*)d_in[8],  // b_ih
      (const float*)d_in[9],  // b_hh
      (const float*)d_in[10], // W_out
      (const float*)d_in[11], // b_out
      (const int*)d_in[12],   // n_chunks
      (float*)d_out);
}

// Round 12
// 18658.286 us; speedup vs baseline: 1.0355x; 1.0355x over previous
//
#include <hip/hip_runtime.h>

// PositionCloser round 12: stream weights from cache, not registers.
// R1-R11 evidence: any >=64-word resident weight array gets AGPR-parked
// (one v_accvgpr_read per use ~= 256 cy/step, the dominant cost), and no
// attribute/pin flips the allocator. Fix: weights live in d_ws as packed f16
// (32 KB, staged once per launch); the compute wave LOADS 32 int4 per step
// through a laundered offset (defeats LICM -> no resident array, no AGPRs).
// Loads are L1/L2-hot, issue on the VMEM pipe, scheduled early w/ vmcnt.
// Shell = R9 (passed, 87% VALUBusy): producer wave + lagged loss wave per
// sequence, LDS h-ring, chunk-granular flags. 1024 blocks x 128 = 2048 waves.

#define CH  128
#define HID 64

typedef __fp16 f16x2 __attribute__((ext_vector_type(2)));

__device__ __forceinline__ float rlf(float v, int l) {
  return __builtin_bit_cast(float, __builtin_amdgcn_readlane(__builtin_bit_cast(int, v), l));
}
__device__ __forceinline__ int rli(int v, int l) { return __builtin_amdgcn_readlane(v, l); }
__device__ __forceinline__ int packh(float a, float b) {
  return __builtin_bit_cast(int, __builtin_amdgcn_cvt_pkrtz(a, b));
}
__device__ __forceinline__ f16x2 h2(int v) { return __builtin_bit_cast(f16x2, v); }
__device__ __forceinline__ float frcp(float x) { return __builtin_amdgcn_rcpf(x); }
__device__ __forceinline__ float sigm(float x) { return frcp(1.0f + __expf(-x)); }
__device__ __forceinline__ float tanh_(float x) {
  float e = __expf(2.0f * x);
  return 1.0f - 2.0f * frcp(e + 1.0f);
}
template <int CTRL, int RMASK>
__device__ __forceinline__ float dpp_add(float v) {
  int x = __builtin_amdgcn_update_dpp(0, __builtin_bit_cast(int, v), CTRL, RMASK, 0xF, true);
  return v + __builtin_bit_cast(float, x);
}
__device__ __forceinline__ float dpp_xor1(float v) {  // quad_perm [1,0,3,2]
  int x = __builtin_amdgcn_update_dpp(0, __builtin_bit_cast(int, v), 0xB1, 0xF, 0xF, true);
  return __builtin_bit_cast(float, x);
}
__device__ __forceinline__ float dpp_wave_sum(float v) {  // total lands in lane 63
  v = dpp_add<0x111, 0xF>(v);
  v = dpp_add<0x112, 0xF>(v);
  v = dpp_add<0x114, 0xF>(v);
  v = dpp_add<0x118, 0xF>(v);
  v = dpp_add<0x142, 0xA>(v);   // row_bcast:15
  v = dpp_add<0x143, 0xC>(v);   // row_bcast:31
  return v;
}

// ---- stage W_hh (f32, [4*64 rows][64 cols]) -> d_ws packed f16 quads:
// ws[j*64 + lane] = { packh(W_g[row=lane][2j],[2j+1]) for g = i,f,g,o }
__global__ void stage_w(const float* __restrict__ W_hh, int4* __restrict__ ws) {
  const int lane = threadIdx.x;   // row within each gate
  const int j    = blockIdx.x;    // K-pair 0..31
  const int k    = 2 * j;
  int4 v;
  v.x = packh(W_hh[(0 * HID + lane) * HID + k], W_hh[(0 * HID + lane) * HID + k + 1]);
  v.y = packh(W_hh[(1 * HID + lane) * HID + k], W_hh[(1 * HID + lane) * HID + k + 1]);
  v.z = packh(W_hh[(2 * HID + lane) * HID + k], W_hh[(2 * HID + lane) * HID + k + 1]);
  v.w = packh(W_hh[(3 * HID + lane) * HID + k], W_hh[(3 * HID + lane) * HID + k + 1]);
  ws[j * 64 + lane] = v;
}

__global__ __attribute__((amdgpu_flat_work_group_size(128, 128), amdgpu_waves_per_eu(2, 2)))
void pc_lstm_kernel(const int* __restrict__ inds,
                    const float* __restrict__ p,
                    const float* __restrict__ ls_probs,
                    const float* __restrict__ open_probs,
                    const int* __restrict__ open_slices,
                    const float* __restrict__ open_hx,
                    const float* __restrict__ W_ih,
                    const float* __restrict__ b_ih,
                    const float* __restrict__ b_hh,
                    const float* __restrict__ W_out,
                    const float* __restrict__ b_out,
                    const int* __restrict__ n_chunks_p,
                    const int4* __restrict__ wpack,
                    float* __restrict__ out)
{
  __shared__ __fp16 ring[2][CH][HID];   // 32 KB: h history for the lagged loss
  __shared__ int prod;                  // chunks fully written by wave0
  __shared__ int cons;                  // chunks fully consumed by wave1

  const int tid  = threadIdx.x;
  const int wv   = tid >> 6;           // 0 = compute, 1 = loss
  const int lane = tid & 63;
  const int s    = blockIdx.x;         // one sequence per block
  const int n_chunks = n_chunks_p[0];
  const int tbase = inds[s >> 4] + (s & 15);
  const float2* p2 = (const float2*)p;

  if (tid == 0) { prod = 0; cons = 0; }
  __syncthreads();                      // only barrier in the kernel

  if (wv == 0) {
    // ================= compute wave =================
    float wxa[4], wxb[4], bb[4];
#pragma unroll
    for (int g = 0; g < 4; ++g) {
      const int r = g * HID + lane;
      wxa[g] = W_ih[2 * r];
      wxb[g] = W_ih[2 * r + 1];
      bb[g]  = b_ih[r] + b_hh[r];
    }
    float h = open_hx[(s * 2 + 0) * HID + lane];
    float c = open_hx[(s * 2 + 1) * HID + lane];

    float2 curA = p2[tbase + lane];
    float2 curB = p2[tbase + HID + lane];
    float2 nxtA = curA, nxtB = curB;

    int woff = lane * (int)sizeof(int4);        // byte offset of this lane's quad

    for (int off = 0; off < n_chunks; ++off) {
      if (off) { curA = nxtA; curB = nxtB; }
      const float px0 = rlf(curA.x, 0);
      const float px1 = rlf(curA.y, 0);
      float2 xA, xB;                             // pre-subtracted chunk base
      xA.x = curA.x - px0; xA.y = curA.y - px1;
      xB.x = curB.x - px0; xB.y = curB.y - px1;
      if (off + 1 < n_chunks) {
        const int nb = tbase + (off + 1) * CH;
        nxtA = p2[nb + lane];
        nxtB = p2[nb + HID + lane];
      }
      while (__hip_atomic_load(&cons, __ATOMIC_ACQUIRE, __HIP_MEMORY_SCOPE_WORKGROUP) + 2 <= off)
        __builtin_amdgcn_s_sleep(8);

      __fp16* slot = &ring[off & 1][0][0];
#pragma unroll
      for (int hf = 0; hf < 2; ++hf) {
        const float xcx = hf ? xB.x : xA.x;
        const float xcy = hf ? xB.y : xA.y;
#pragma unroll 1
        for (int tl = 0; tl < 64; ++tl) {
          // launder the weight offset: compiler can't hoist loads across steps,
          // so no resident weight array exists to be AGPR-parked.
          asm volatile("" : "+v"(woff));
          const int4* wp = (const int4*)((const char*)wpack + woff);

          const int hp = packh(h, dpp_xor1(h));   // even lane 2j: (h_2j, h_2j+1)
          const float x0 = rlf(xcx, tl);
          const float x1 = rlf(xcy, tl);

          float A0 = bb[0], A1 = bb[1], A2 = bb[2], A3 = bb[3];
          float B0 = fmaf(x1, wxb[0], x0 * wxa[0]);
          float B1 = fmaf(x1, wxb[1], x0 * wxa[1]);
          float B2 = fmaf(x1, wxb[2], x0 * wxa[2]);
          float B3 = fmaf(x1, wxb[3], x0 * wxa[3]);
#pragma unroll
          for (int j = 0; j < 16; ++j) {
            const int4 wa = wp[j * 64];           // K-pair j     (L1/L2-hot)
            const int4 wb = wp[(j + 16) * 64];    // K-pair j+16
            const f16x2 ha = h2(rli(hp, 2 * j));
            const f16x2 hb = h2(rli(hp, 2 * j + 32));
            A0 = __builtin_amdgcn_fdot2(ha, h2(wa.x), A0, false);
            B0 = __builtin_amdgcn_fdot2(hb, h2(wb.x), B0, false);
            A1 = __builtin_amdgcn_fdot2(ha, h2(wa.y), A1, false);
            B1 = __builtin_amdgcn_fdot2(hb, h2(wb.y), B1, false);
            A2 = __builtin_amdgcn_fdot2(ha, h2(wa.z), A2, false);
            B2 = __builtin_amdgcn_fdot2(hb, h2(wb.z), B2, false);
            A3 = __builtin_amdgcn_fdot2(ha, h2(wa.w), A3, false);
            B3 = __builtin_amdgcn_fdot2(hb, h2(wb.w), B3, false);
          }
          const float ig = sigm(A0 + B0);
          const float fg = sigm(A1 + B1);
          const float gg = tanh_(A2 + B2);
          const float og = sigm(A3 + B3);
          c = fmaf(fg, c, ig * gg);
          h = og * tanh_(c);

          slot[(hf * 64 + tl) * HID + lane] = (__fp16)h;   // ds_write_b16
        }
      }
      if (lane == 0)
        __hip_atomic_store(&prod, off + 1, __ATOMIC_RELEASE, __HIP_MEMORY_SCOPE_WORKGROUP);
    }
  } else {
    // ================= loss wave =================
    const float wo   = W_out[lane];
    const float bout = b_out[0];
    const int   os   = open_slices[s];
    const float OL   = __logf(p[2 * os]) + __logf(p[2 * os + 1]);
    const float coef = open_probs[s] * (2.0f * ls_probs[s] - 1.0f);

    float S = 1.0f, D = 1.0f, lsum = 0.0f, psum = 0.0f;

    for (int off = 0; off < n_chunks; ++off) {
      const int cb = tbase + off * CH;
      const float2 cA = p2[cb + lane];
      const float2 cB = p2[cb + HID + lane];
      const float LA = __logf(cA.x) + __logf(cA.y);
      const float LB = __logf(cB.x) + __logf(cB.y);

      while (__hip_atomic_load(&prod, __ATOMIC_ACQUIRE, __HIP_MEMORY_SCOPE_WORKGROUP) <= off)
        __builtin_amdgcn_s_sleep(32);

      const __fp16* slot = &ring[off & 1][0][0];
#pragma unroll 1
      for (int tt = 0; tt < CH; ++tt) {
        const float hv = (float)slot[tt * HID + lane];
        const float z  = rlf(dpp_wave_sum(hv * wo), 63);
        const float pr = sigm(z + bout);
        const float Lt = (tt < 64) ? rlf(LA, tt) : rlf(LB, tt - 64);
        const float pn = (tt == 0) ? pr : pr * D;
        lsum = fmaf(pn, Lt, lsum);
        psum += pn;
        if (tt == 0)           D = S * (1.0f - pr);   // chunk t=0 undiscounted (ref quirk)
        else if (tt < CH - 1)  D *= (1.0f - pr);
        else                   S = D;                  // carry excludes (1-p_last)
      }
      if (lane == 0)
        __hip_atomic_store(&cons, off + 1, __ATOMIC_RELEASE, __HIP_MEMORY_SCOPE_WORKGROUP);
    }
    if (lane == 0) atomicAdd(out, coef * (lsum - OL * psum));
  }
}

extern "C" void kernel_launch(void* const* d_in, const int* in_sizes, int n_in,
                              void* d_out, int out_size, void* d_ws, size_t ws_size,
                              hipStream_t stream) {
  (void)hipMemsetAsync(d_out, 0, sizeof(float), stream);

  // stage packed-f16 weight quads into d_ws (32 KB; ws is re-poisoned each call)
  stage_w<<<dim3(32), dim3(64), 0, stream>>>((const float*)d_in[7], (int4*)d_ws);

  pc_lstm_kernel<<<dim3(1024), dim3(128), 0, stream>>>(
      (const int*)d_in[0],    // inds
      (const float*)d_in[1],  // p
      (const float*)d_in[2],  // ls_probs
      (const float*)d_in[3],  // open_probs
      (const int*)d_in[4],    // open_slices
      (const float*)d_in[5],  // open_hx
      (const float*)d_in[6],  // W_ih
      (const float*)d_in[8],  // b_ih
      (const float*)d_in[9],  // b_hh
      (const float*)d_in[10], // W_out
      (const float*)d_in[11], // b_out
      (const int*)d_in[12],   // n_chunks
      (const int4*)d_ws,      // packed weights
      (float*)d_out);
}

// Round 13
// 7999.153 us; speedup vs baseline: 2.4153x; 2.3325x over previous
//
#include <hip/hip_runtime.h>

// PositionCloser round 13: R9 shell + asm-forced arch-VGPR weights.
// R12 proved weights must be register-resident (32KB/wave/step exceeds L1 BW);
// R1-R11 proved the allocator AGPR-parks the 128-word array and VALU can't
// read AGPRs -> one v_accvgpr_read per use. Fix: the v_dot2 consumers are
// inline asm with "v"-constrained weight INPUTS (arch-VGPR class only) inside
// the hot loop -> allocator must home them architecturally. h broadcast = 32
// v_readlane into SGPRs (the single legal SGPR src of VOP3P), shared across
// all 4 gate blocks. Shell identical to R9: compute+loss waves, h-ring, flags.

#define CH  128
#define HID 64

__device__ __forceinline__ float rlf(float v, int l) {
  return __builtin_bit_cast(float, __builtin_amdgcn_readlane(__builtin_bit_cast(int, v), l));
}
__device__ __forceinline__ int rli(int v, int l) { return __builtin_amdgcn_readlane(v, l); }
__device__ __forceinline__ int packh(float a, float b) {
  return __builtin_bit_cast(int, __builtin_amdgcn_cvt_pkrtz(a, b));
}
__device__ __forceinline__ float frcp(float x) { return __builtin_amdgcn_rcpf(x); }
__device__ __forceinline__ float sigm(float x) { return frcp(1.0f + __expf(-x)); }
__device__ __forceinline__ float tanh_(float x) {
  float e = __expf(2.0f * x);
  return 1.0f - 2.0f * frcp(e + 1.0f);
}
template <int CTRL, int RMASK>
__device__ __forceinline__ float dpp_add(float v) {
  int x = __builtin_amdgcn_update_dpp(0, __builtin_bit_cast(int, v), CTRL, RMASK, 0xF, true);
  return v + __builtin_bit_cast(float, x);
}
__device__ __forceinline__ float dpp_xor1(float v) {  // quad_perm [1,0,3,2]
  int x = __builtin_amdgcn_update_dpp(0, __builtin_bit_cast(int, v), 0xB1, 0xF, 0xF, true);
  return __builtin_bit_cast(float, x);
}
__device__ __forceinline__ float dpp_wave_sum(float v) {  // total lands in lane 63
  v = dpp_add<0x111, 0xF>(v);
  v = dpp_add<0x112, 0xF>(v);
  v = dpp_add<0x114, 0xF>(v);
  v = dpp_add<0x118, 0xF>(v);
  v = dpp_add<0x142, 0xA>(v);   // row_bcast:15
  v = dpp_add<0x143, 0xC>(v);   // row_bcast:31
  return v;
}

// 32 dots for one gate: two interleaved 16-chains (A: k=0..15, B: k=16..31).
// Weights are "v"-constrained (architectural VGPR class) -> no AGPR homes.
#define DOTS(A, B, W) asm( \
  "v_dot2_f32_f16 %[a], %[h0], %[w0], %[a]\n\t"   \
  "v_dot2_f32_f16 %[b], %[h16], %[w16], %[b]\n\t" \
  "v_dot2_f32_f16 %[a], %[h1], %[w1], %[a]\n\t"   \
  "v_dot2_f32_f16 %[b], %[h17], %[w17], %[b]\n\t" \
  "v_dot2_f32_f16 %[a], %[h2], %[w2], %[a]\n\t"   \
  "v_dot2_f32_f16 %[b], %[h18], %[w18], %[b]\n\t" \
  "v_dot2_f32_f16 %[a], %[h3], %[w3], %[a]\n\t"   \
  "v_dot2_f32_f16 %[b], %[h19], %[w19], %[b]\n\t" \
  "v_dot2_f32_f16 %[a], %[h4], %[w4], %[a]\n\t"   \
  "v_dot2_f32_f16 %[b], %[h20], %[w20], %[b]\n\t" \
  "v_dot2_f32_f16 %[a], %[h5], %[w5], %[a]\n\t"   \
  "v_dot2_f32_f16 %[b], %[h21], %[w21], %[b]\n\t" \
  "v_dot2_f32_f16 %[a], %[h6], %[w6], %[a]\n\t"   \
  "v_dot2_f32_f16 %[b], %[h22], %[w22], %[b]\n\t" \
  "v_dot2_f32_f16 %[a], %[h7], %[w7], %[a]\n\t"   \
  "v_dot2_f32_f16 %[b], %[h23], %[w23], %[b]\n\t" \
  "v_dot2_f32_f16 %[a], %[h8], %[w8], %[a]\n\t"   \
  "v_dot2_f32_f16 %[b], %[h24], %[w24], %[b]\n\t" \
  "v_dot2_f32_f16 %[a], %[h9], %[w9], %[a]\n\t"   \
  "v_dot2_f32_f16 %[b], %[h25], %[w25], %[b]\n\t" \
  "v_dot2_f32_f16 %[a], %[h10], %[w10], %[a]\n\t" \
  "v_dot2_f32_f16 %[b], %[h26], %[w26], %[b]\n\t" \
  "v_dot2_f32_f16 %[a], %[h11], %[w11], %[a]\n\t" \
  "v_dot2_f32_f16 %[b], %[h27], %[w27], %[b]\n\t" \
  "v_dot2_f32_f16 %[a], %[h12], %[w12], %[a]\n\t" \
  "v_dot2_f32_f16 %[b], %[h28], %[w28], %[b]\n\t" \
  "v_dot2_f32_f16 %[a], %[h13], %[w13], %[a]\n\t" \
  "v_dot2_f32_f16 %[b], %[h29], %[w29], %[b]\n\t" \
  "v_dot2_f32_f16 %[a], %[h14], %[w14], %[a]\n\t" \
  "v_dot2_f32_f16 %[b], %[h30], %[w30], %[b]\n\t" \
  "v_dot2_f32_f16 %[a], %[h15], %[w15], %[a]\n\t" \
  "v_dot2_f32_f16 %[b], %[h31], %[w31], %[b]"     \
  : [a] "+v"(A), [b] "+v"(B) \
  : [h0] "s"(hs[0]),   [h1] "s"(hs[1]),   [h2] "s"(hs[2]),   [h3] "s"(hs[3]),   \
    [h4] "s"(hs[4]),   [h5] "s"(hs[5]),   [h6] "s"(hs[6]),   [h7] "s"(hs[7]),   \
    [h8] "s"(hs[8]),   [h9] "s"(hs[9]),   [h10] "s"(hs[10]), [h11] "s"(hs[11]), \
    [h12] "s"(hs[12]), [h13] "s"(hs[13]), [h14] "s"(hs[14]), [h15] "s"(hs[15]), \
    [h16] "s"(hs[16]), [h17] "s"(hs[17]), [h18] "s"(hs[18]), [h19] "s"(hs[19]), \
    [h20] "s"(hs[20]), [h21] "s"(hs[21]), [h22] "s"(hs[22]), [h23] "s"(hs[23]), \
    [h24] "s"(hs[24]), [h25] "s"(hs[25]), [h26] "s"(hs[26]), [h27] "s"(hs[27]), \
    [h28] "s"(hs[28]), [h29] "s"(hs[29]), [h30] "s"(hs[30]), [h31] "s"(hs[31]), \
    [w0] "v"(W[0]),   [w1] "v"(W[1]),   [w2] "v"(W[2]),   [w3] "v"(W[3]),   \
    [w4] "v"(W[4]),   [w5] "v"(W[5]),   [w6] "v"(W[6]),   [w7] "v"(W[7]),   \
    [w8] "v"(W[8]),   [w9] "v"(W[9]),   [w10] "v"(W[10]), [w11] "v"(W[11]), \
    [w12] "v"(W[12]), [w13] "v"(W[13]), [w14] "v"(W[14]), [w15] "v"(W[15]), \
    [w16] "v"(W[16]), [w17] "v"(W[17]), [w18] "v"(W[18]), [w19] "v"(W[19]), \
    [w20] "v"(W[20]), [w21] "v"(W[21]), [w22] "v"(W[22]), [w23] "v"(W[23]), \
    [w24] "v"(W[24]), [w25] "v"(W[25]), [w26] "v"(W[26]), [w27] "v"(W[27]), \
    [w28] "v"(W[28]), [w29] "v"(W[29]), [w30] "v"(W[30]), [w31] "v"(W[31]))

__global__ __attribute__((amdgpu_flat_work_group_size(128, 128), amdgpu_waves_per_eu(2, 2)))
void pc_lstm_kernel(const int* __restrict__ inds,
                    const float* __restrict__ p,
                    const float* __restrict__ ls_probs,
                    const float* __restrict__ open_probs,
                    const int* __restrict__ open_slices,
                    const float* __restrict__ open_hx,
                    const float* __restrict__ W_ih,
                    const float* __restrict__ W_hh,
                    const float* __restrict__ b_ih,
                    const float* __restrict__ b_hh,
                    const float* __restrict__ W_out,
                    const float* __restrict__ b_out,
                    const int* __restrict__ n_chunks_p,
                    float* __restrict__ out)
{
  __shared__ __fp16 ring[2][CH][HID];   // 32 KB: h history for the lagged loss
  __shared__ int prod;                  // chunks fully written by wave0
  __shared__ int cons;                  // chunks fully consumed by wave1

  const int tid  = threadIdx.x;
  const int wv   = tid >> 6;           // 0 = compute, 1 = loss
  const int lane = tid & 63;
  const int s    = blockIdx.x;         // one sequence per block
  const int n_chunks = n_chunks_p[0];
  const int tbase = inds[s >> 4] + (s & 15);
  const float2* p2 = (const float2*)p;

  if (tid == 0) { prod = 0; cons = 0; }
  __syncthreads();                      // only barrier in the kernel

  if (wv == 0) {
    // ================= compute wave =================
    int W0[32], W1[32], W2[32], W3[32];   // packed f16x2, lane owns rows g*64+lane
    {
      const float2* r0 = (const float2*)(W_hh + (0 * HID + lane) * HID);
      const float2* r1 = (const float2*)(W_hh + (1 * HID + lane) * HID);
      const float2* r2 = (const float2*)(W_hh + (2 * HID + lane) * HID);
      const float2* r3 = (const float2*)(W_hh + (3 * HID + lane) * HID);
#pragma unroll
      for (int j = 0; j < 32; ++j) {
        float2 v0 = r0[j], v1 = r1[j], v2 = r2[j], v3 = r3[j];
        W0[j] = packh(v0.x, v0.y);
        W1[j] = packh(v1.x, v1.y);
        W2[j] = packh(v2.x, v2.y);
        W3[j] = packh(v3.x, v3.y);
      }
    }
    float wxa[4], wxb[4], bb[4];
#pragma unroll
    for (int g = 0; g < 4; ++g) {
      const int r = g * HID + lane;
      wxa[g] = W_ih[2 * r];
      wxb[g] = W_ih[2 * r + 1];
      bb[g]  = b_ih[r] + b_hh[r];
    }
    float h = open_hx[(s * 2 + 0) * HID + lane];
    float c = open_hx[(s * 2 + 1) * HID + lane];

    float2 curA = p2[tbase + lane];
    float2 curB = p2[tbase + HID + lane];
    float2 nxtA = curA, nxtB = curB;

    for (int off = 0; off < n_chunks; ++off) {
      if (off) { curA = nxtA; curB = nxtB; }
      const float px0 = rlf(curA.x, 0);
      const float px1 = rlf(curA.y, 0);
      float2 xA, xB;                       // pre-subtracted chunk base
      xA.x = curA.x - px0; xA.y = curA.y - px1;
      xB.x = curB.x - px0; xB.y = curB.y - px1;
      if (off + 1 < n_chunks) {
        const int nb = tbase + (off + 1) * CH;
        nxtA = p2[nb + lane];
        nxtB = p2[nb + HID + lane];
      }
      while (__hip_atomic_load(&cons, __ATOMIC_ACQUIRE, __HIP_MEMORY_SCOPE_WORKGROUP) + 2 <= off)
        __builtin_amdgcn_s_sleep(8);

      __fp16* slot = &ring[off & 1][0][0];
#pragma unroll
      for (int hf = 0; hf < 2; ++hf) {
        const float xcx = hf ? xB.x : xA.x;
        const float xcy = hf ? xB.y : xA.y;
#pragma unroll 1
        for (int tl = 0; tl < 64; ++tl) {
          const int hp = packh(h, dpp_xor1(h));   // even lane 2j: (h_2j, h_2j+1)
          int hs[32];
#pragma unroll
          for (int j = 0; j < 32; ++j) hs[j] = rli(hp, 2 * j);  // SGPR broadcasts

          const float x0 = rlf(xcx, tl);
          const float x1 = rlf(xcy, tl);

          float A0 = fmaf(x0, wxa[0], bb[0]), B0 = x1 * wxb[0];
          float A1 = fmaf(x0, wxa[1], bb[1]), B1 = x1 * wxb[1];
          float A2 = fmaf(x0, wxa[2], bb[2]), B2 = x1 * wxb[2];
          float A3 = fmaf(x0, wxa[3], bb[3]), B3 = x1 * wxb[3];

          DOTS(A0, B0, W0);
          DOTS(A1, B1, W1);
          DOTS(A2, B2, W2);
          DOTS(A3, B3, W3);

          const float ig = sigm(A0 + B0);
          const float fg = sigm(A1 + B1);
          const float gg = tanh_(A2 + B2);
          const float og = sigm(A3 + B3);
          c = fmaf(fg, c, ig * gg);
          h = og * tanh_(c);

          slot[(hf * 64 + tl) * HID + lane] = (__fp16)h;   // ds_write_b16
        }
      }
      if (lane == 0)
        __hip_atomic_store(&prod, off + 1, __ATOMIC_RELEASE, __HIP_MEMORY_SCOPE_WORKGROUP);
    }
  } else {
    // ================= loss wave =================
    const float wo   = W_out[lane];
    const float bout = b_out[0];
    const int   os   = open_slices[s];
    const float OL   = __logf(p[2 * os]) + __logf(p[2 * os + 1]);
    const float coef = open_probs[s] * (2.0f * ls_probs[s] - 1.0f);

    float S = 1.0f, D = 1.0f, lsum = 0.0f, psum = 0.0f;

    for (int off = 0; off < n_chunks; ++off) {
      const int cb = tbase + off * CH;
      const float2 cA = p2[cb + lane];
      const float2 cB = p2[cb + HID + lane];
      const float LA = __logf(cA.x) + __logf(cA.y);
      const float LB = __logf(cB.x) + __logf(cB.y);

      while (__hip_atomic_load(&prod, __ATOMIC_ACQUIRE, __HIP_MEMORY_SCOPE_WORKGROUP) <= off)
        __builtin_amdgcn_s_sleep(32);

      const __fp16* slot = &ring[off & 1][0][0];
#pragma unroll 1
      for (int tt = 0; tt < CH; ++tt) {
        const float hv = (float)slot[tt * HID + lane];
        const float z  = rlf(dpp_wave_sum(hv * wo), 63);
        const float pr = sigm(z + bout);
        const float Lt = (tt < 64) ? rlf(LA, tt) : rlf(LB, tt - 64);
        const float pn = (tt == 0) ? pr : pr * D;
        lsum = fmaf(pn, Lt, lsum);
        psum += pn;
        if (tt == 0)           D = S * (1.0f - pr);   // chunk t=0 undiscounted (ref quirk)
        else if (tt < CH - 1)  D *= (1.0f - pr);
        else                   S = D;                  // carry excludes (1-p_last)
      }
      if (lane == 0)
        __hip_atomic_store(&cons, off + 1, __ATOMIC_RELEASE, __HIP_MEMORY_SCOPE_WORKGROUP);
    }
    if (lane == 0) atomicAdd(out, coef * (lsum - OL * psum));
  }
}

extern "C" void kernel_launch(void* const* d_in, const int* in_sizes, int n_in,
                              void* d_out, int out_size, void* d_ws, size_t ws_size,
                              hipStream_t stream) {
  (void)hipMemsetAsync(d_out, 0, sizeof(float), stream);

  pc_lstm_kernel<<<dim3(1024), dim3(128), 0, stream>>>(
      (const int*)d_in[0],    // inds
      (const float*)d_in[1],  // p
      (const float*)d_in[2],  // ls_probs
      (const float*)d_in[3],  // open_probs
      (const int*)d_in[4],    // open_slices
      (const float*)d_in[5],  // open_hx
      (const float*)d_in[6],  // W_ih
      (const float*)d_in[7],  // W_hh
      (const float*)d_in[8],  // b_ih
      (const float*)d_in[9],  // b_hh
      (const float*)d_in[10], // W_out
      (const float*)d_in[11], // b_out
      (const int*)d_in[12],   // n_chunks
      (float*)d_out);
}